// Round 11
// baseline (1777.316 us; speedup 1.0000x reference)
//
#include <hip/hip_runtime.h>
#include <hip/hip_fp16.h>

#define N_VAR 256
#define M_CON 512
#define BATCH 64
#define SIGMA_C 1e-6f
#define RHO_C 0.1f
#define ALPHA_C 1.6f
#define NITERS 500

// ---------------------------------------------------------------------------
// K1: transpose A [512][256] -> At [256][512] per batch
// ---------------------------------------------------------------------------
__global__ __launch_bounds__(256) void k_transpose(const float* __restrict__ A,
                                                   float* __restrict__ At) {
  __shared__ float tile[32][33];
  int b = blockIdx.z;
  int n0 = blockIdx.x * 32;
  int m0 = blockIdx.y * 32;
  const float* Ab = A + (size_t)b * (M_CON * N_VAR);
  float* Atb = At + (size_t)b * (M_CON * N_VAR);
  int tx = threadIdx.x, ty = threadIdx.y;  // (32, 8)
#pragma unroll
  for (int j = 0; j < 32; j += 8)
    tile[ty + j][tx] = Ab[(size_t)(m0 + ty + j) * N_VAR + n0 + tx];
  __syncthreads();
#pragma unroll
  for (int j = 0; j < 32; j += 8)
    Atb[(size_t)(n0 + ty + j) * M_CON + m0 + tx] = tile[tx][ty + j];
}

// ---------------------------------------------------------------------------
// K2: batched NT GEMM, double-buffered LDS, padded rows (132) -> conflict-free
// staging (round-10). symN>0: upper tiles only; k_mirror fills the rest.
// ---------------------------------------------------------------------------
__global__ __launch_bounds__(256) void k_ntgemm(
    const float* __restrict__ X, const float* __restrict__ Y,
    float* __restrict__ C, int J, int K,
    long long bsX, long long bsY, long long bsC, float alpha,
    const float* __restrict__ diagv, int tilesJ, int symN) {
  int b = blockIdx.y;
  int ti, tj;
  if (symN > 0) {
    int r = blockIdx.x;
    ti = 0;
    while (r >= symN - ti) { r -= (symN - ti); ++ti; }
    tj = ti + r;
  } else {
    ti = blockIdx.x / tilesJ;
    tj = blockIdx.x % tilesJ;
  }
  int i0 = ti * 128, j0 = tj * 128;
  const float* Xb = X + (size_t)b * bsX;
  const float* Yb = Y + (size_t)b * bsY;
  float* Cb = C + (size_t)b * bsC;
  __shared__ float Xs[2][16][132];
  __shared__ float Ys[2][16][132];
  int tid = threadIdx.x;
  int tx = tid & 15, ty = tid >> 4;
  int row0 = tid >> 2, k40 = (tid & 3) * 4;

  float acc[8][8];
#pragma unroll
  for (int r = 0; r < 8; ++r)
#pragma unroll
    for (int c = 0; c < 8; ++c) acc[r][c] = 0.0f;

  float4 rx0, rx1, ry0, ry1;
  auto prefetch = [&](int kk) {
    rx0 = *(const float4*)(Xb + (size_t)(i0 + row0) * K + kk + k40);
    rx1 = *(const float4*)(Xb + (size_t)(i0 + row0 + 64) * K + kk + k40);
    ry0 = *(const float4*)(Yb + (size_t)(j0 + row0) * K + kk + k40);
    ry1 = *(const float4*)(Yb + (size_t)(j0 + row0 + 64) * K + kk + k40);
  };
  auto commit = [&](int buf) {
    Xs[buf][k40 + 0][row0] = rx0.x; Xs[buf][k40 + 1][row0] = rx0.y;
    Xs[buf][k40 + 2][row0] = rx0.z; Xs[buf][k40 + 3][row0] = rx0.w;
    Xs[buf][k40 + 0][row0 + 64] = rx1.x; Xs[buf][k40 + 1][row0 + 64] = rx1.y;
    Xs[buf][k40 + 2][row0 + 64] = rx1.z; Xs[buf][k40 + 3][row0 + 64] = rx1.w;
    Ys[buf][k40 + 0][row0] = ry0.x; Ys[buf][k40 + 1][row0] = ry0.y;
    Ys[buf][k40 + 2][row0] = ry0.z; Ys[buf][k40 + 3][row0] = ry0.w;
    Ys[buf][k40 + 0][row0 + 64] = ry1.x; Ys[buf][k40 + 1][row0 + 64] = ry1.y;
    Ys[buf][k40 + 2][row0 + 64] = ry1.z; Ys[buf][k40 + 3][row0 + 64] = ry1.w;
  };

  int nkt = K >> 4;
  prefetch(0);
  commit(0);
  __syncthreads();

  for (int kt = 0; kt < nkt; ++kt) {
    int cur = kt & 1;
    if (kt + 1 < nkt) prefetch((kt + 1) * 16);
#pragma unroll
    for (int k = 0; k < 16; ++k) {
      float xr[8], yr[8];
      *(float4*)&xr[0] = *(float4*)&Xs[cur][k][ty * 8];
      *(float4*)&xr[4] = *(float4*)&Xs[cur][k][ty * 8 + 4];
      *(float4*)&yr[0] = *(float4*)&Ys[cur][k][tx * 8];
      *(float4*)&yr[4] = *(float4*)&Ys[cur][k][tx * 8 + 4];
#pragma unroll
      for (int r = 0; r < 8; ++r)
#pragma unroll
        for (int c = 0; c < 8; ++c) acc[r][c] += xr[r] * yr[c];
    }
    if (kt + 1 < nkt) commit(cur ^ 1);
    __syncthreads();
  }

#pragma unroll
  for (int r = 0; r < 8; ++r) {
    int gi = i0 + ty * 8 + r;
#pragma unroll
    for (int c = 0; c < 8; ++c) {
      int gj = j0 + tx * 8 + c;
      float val = acc[r][c] * alpha;
      if (diagv != nullptr && gi == gj) val += diagv[(size_t)b * N_VAR + gi] + SIGMA_C;
      Cb[(size_t)gi * J + gj] = val;
    }
  }
}

// ---------------------------------------------------------------------------
// K2b: mirror upper triangle -> lower for symmetric n x n.
// ---------------------------------------------------------------------------
__global__ __launch_bounds__(256) void k_mirror(float* __restrict__ C, int n,
                                                long long bsC) {
  __shared__ float tile[32][33];
  int b = blockIdx.y;
  int idx = blockIdx.x;
  int bi = 1;
  while (idx >= bi) { idx -= bi; ++bi; }
  int bj = idx;
  float* Cb = C + (size_t)b * bsC;
  int tx = threadIdx.x & 31, ty = threadIdx.x >> 5;  // 32 x 8
#pragma unroll
  for (int j = 0; j < 32; j += 8)
    tile[ty + j][tx] = Cb[(size_t)(bj * 32 + ty + j) * n + bi * 32 + tx];
  __syncthreads();
#pragma unroll
  for (int j = 0; j < 32; j += 8)
    Cb[(size_t)(bi * 32 + ty + j) * n + bj * 32 + tx] = tile[tx][ty + j];
}

// ---------------------------------------------------------------------------
// K3: BLOCKED Gauss-Jordan inversion, NB=8 (round-7 version).
// ---------------------------------------------------------------------------
__global__ __launch_bounds__(512, 2) void k_invert(const float* __restrict__ Mk,
                                                   float* __restrict__ Mi) {
  int b = blockIdx.x;
  const float* src = Mk + (size_t)b * 65536;
  float* dst = Mi + (size_t)b * 65536;
  int t = threadIdx.x;
  int c = t & 255, rh = t >> 8;

  float a[128];
#pragma unroll
  for (int j = 0; j < 128; ++j) a[j] = src[(size_t)(rh * 128 + j) * 256 + c];

  __shared__ float colPan[256][8];
  __shared__ float rowPan[2][8][260];
  __shared__ float PiSh[64];
  __shared__ float Rp[8][260];

  int rh_s = __builtin_amdgcn_readfirstlane(rh);
  int cw_s = __builtin_amdgcn_readfirstlane((t >> 6) & 3);

  if (rh == 0) {
#pragma unroll
    for (int j = 0; j < 8; ++j) rowPan[0][j][c] = a[j];
  }
  __syncthreads();

  for (int s = 0; s < 32; ++s) {
    int kb = s * 8;
    int cur = s & 1, nxt = cur ^ 1;
    int kh = kb >> 7, kj = kb & 127;
    int khn = (kb + 8) >> 7, kjn = (kb + 8) & 127;
    bool mycol = (c >= kb) && (c < kb + 8);

    if (cw_s == (kb >> 6)) {
      if (mycol) {
        int f = c - kb;
#pragma unroll
        for (int j = 0; j < 128; ++j) colPan[rh * 128 + j][f] = a[j];
      }
    }
    if (t < 64) {
      int e = t >> 3, f = t & 7;
      float p = rowPan[cur][e][kb + f];
#pragma unroll
      for (int k2 = 0; k2 < 8; ++k2) {
        float piv = __shfl(p, k2 * 8 + k2);
        float rv = __shfl(p, k2 * 8 + f);
        float cv = __shfl(p, e * 8 + k2);
        float pivinv = 1.0f / piv;
        float srv = rv * pivinv;
        float gen = p - cv * srv;
        p = gen;
        if (e == k2) p = srv;
        if (f == k2) p = -cv * pivinv;
        if (e == k2 && f == k2) p = pivinv;
      }
      PiSh[t] = p;
    }
    __syncthreads();

    float rpan[8];
#pragma unroll
    for (int f2 = 0; f2 < 8; ++f2) rpan[f2] = rowPan[cur][f2][c];
    float rp[8];
#pragma unroll
    for (int e = 0; e < 8; ++e) {
      float4 p0 = *(const float4*)&PiSh[e * 8];
      float4 p1 = *(const float4*)&PiSh[e * 8 + 4];
      rp[e] = p0.x * rpan[0] + p0.y * rpan[1] + p0.z * rpan[2] + p0.w * rpan[3] +
              p1.x * rpan[4] + p1.y * rpan[5] + p1.z * rpan[6] + p1.w * rpan[7];
    }
    if (cw_s == (kb >> 6)) {
      if (mycol) {
        int f = c - kb;
#pragma unroll
        for (int e = 0; e < 8; ++e) rp[e] = PiSh[e * 8 + f];
      }
    }
#pragma unroll
    for (int e = 0; e < 8; ++e) Rp[e][c] = rp[e];

    bool myhalfk = (rh_s == kh);
    bool stashw = (s != 31) && (rh_s == khn);
#pragma unroll
    for (int j = 0; j < 128; ++j) {
      float4 c0 = *(const float4*)&colPan[rh * 128 + j][0];
      float4 c1 = *(const float4*)&colPan[rh * 128 + j][4];
      float aold = a[j];
      float nv = aold -
                 (c0.x * rp[0] + c0.y * rp[1] + c0.z * rp[2] + c0.w * rp[3] +
                  c1.x * rp[4] + c1.y * rp[5] + c1.z * rp[6] + c1.w * rp[7]);
      if (mycol) nv -= aold;
      if (myhalfk && j >= kj && j < kj + 8)
        nv = Rp[j - kj][c];
      a[j] = nv;
      if (stashw && j >= kjn && j < kjn + 8)
        rowPan[nxt][j - kjn][c] = nv;
    }
    __syncthreads();
  }

#pragma unroll
  for (int j = 0; j < 128; ++j) dst[(size_t)(rh * 128 + j) * 256 + c] = a[j];
}

// ---------------------------------------------------------------------------
// K4: fused  h = Minv*q ; d = A*h   (one launch instead of two)
// ---------------------------------------------------------------------------
__global__ __launch_bounds__(512) void k_matvec_hd(
    const float* __restrict__ Mi, const float* __restrict__ q,
    const float* __restrict__ At, float* __restrict__ d) {
  int b = blockIdx.x, t = threadIdx.x;
  __shared__ float qs[256];
  __shared__ float hs[256];
  if (t < 256) qs[t] = q[(size_t)b * 256 + t];
  __syncthreads();
  if (t < 256) {
    const float* Mb = Mi + (size_t)b * 65536;
    float acc = 0.0f;
    for (int k = 0; k < 256; ++k) acc += Mb[(size_t)k * 256 + t] * qs[k];
    hs[t] = acc;
  }
  __syncthreads();
  const float* Ab = At + (size_t)b * 131072;
  float acc = 0.0f;
  for (int n = 0; n < 256; ++n) acc += Ab[(size_t)n * 512 + t] * hs[n];
  d[(size_t)b * 512 + t] = acc;
}

// ---------------------------------------------------------------------------
// K6: ADMM loop, 4 CUs/batch, register-resident G, packed u64 exchange
// (bit63 = row-stable, bits62:32 = iter tag, bits31:0 = w value).
// EARLY EXIT on bitwise fixed point: once ALL 512 rows' (z,y) are bitwise
// unchanged across one iteration, every later iteration repeats exactly ->
// fast-forward S locally (S <- w - 0.6 S, R times, w frozen) and stop.
// Consensus: every WG ANDs the same 512 bits (own 128 via 2 wave ballots,
// remote 384 via the polled packets) -> all WGs exit at the same iteration.
// Parity-double-buffered LDS flags, barrier-separated (no races).
// Worst case (no fixed point): full 500 iters, ~5 extra VALU/iter.
// ---------------------------------------------------------------------------
__global__ __launch_bounds__(512, 2) void k_admm4(
    const float* __restrict__ G, const float* __restrict__ dvec,
    const float* __restrict__ lv, const float* __restrict__ uv,
    unsigned long long* __restrict__ wtag, float* __restrict__ Sbuf) {
  int g = blockIdx.x;
  int b = (g & 7) + 8 * ((g >> 3) & 7);
  int s = g >> 6;
  int t = threadIdx.x;
  int r = t & 31, ck = t >> 5;
  int c0 = ck * 32;

  __shared__ __align__(16) float wloc[512];
  __shared__ float part[16][132];
  __shared__ int ownW[2][2];  // [parity][wave-half] own-slice stability
  __shared__ int remOK[2];    // [parity] AND of remote rows' stability

  // --- one-time: G strip into registers (rows r+32k, cols [c0,c0+32)) ---
  const float* Gb = G + (size_t)b * 262144;
  float Greg[4][32];
#pragma unroll
  for (int k = 0; k < 4; ++k) {
    const float* gp = Gb + (size_t)(s * 128 + r + 32 * k) * 512 + c0;
#pragma unroll
    for (int j = 0; j < 8; ++j) {
      float4 v = *(const float4*)(gp + 4 * j);
      Greg[k][4 * j + 0] = v.x; Greg[k][4 * j + 1] = v.y;
      Greg[k][4 * j + 2] = v.z; Greg[k][4 * j + 3] = v.w;
    }
  }

  float zreg = 0.0f, yreg = 0.0f, Sreg = 0.0f;
  float lreg = 0.0f, ureg = 0.0f, dreg = 0.0f;
  if (t < 128) {
    lreg = lv[(size_t)b * 512 + s * 128 + t];
    ureg = uv[(size_t)b * 512 + s * 128 + t];
    dreg = dvec[(size_t)b * 512 + s * 128 + t];
  }
  wloc[t] = 0.0f;  // w_0 = 0
  if (t == 0) {
    ownW[0][0] = 0; ownW[0][1] = 0; ownW[1][0] = 0; ownW[1][1] = 0;
    remOK[0] = 1; remOK[1] = 1;
  }

  unsigned long long* wt0 = wtag + (size_t)b * 512;
  unsigned long long* wt1 = wtag + 32768 + (size_t)b * 512;
  int gr = (s * 128 + t) & 511;
  const float4* wq4 = (const float4*)(wloc + c0);

  for (int it = 0; it < NITERS; ++it) {
    __syncthreads();  // Btop: wloc == w_it everywhere; flags[it&1] final

    {  // early-exit check (uniform: all threads read same LDS)
      int slot = it & 1;
      if (ownW[slot][0] && ownW[slot][1] && remOK[slot]) {
        if (t < 128) {
          float ww = RHO_C * zreg - yreg;  // frozen w
          int R = NITERS - it;
          for (int i2 = 0; i2 < R; ++i2) Sreg = ww - 0.6f * Sreg;
        }
        break;
      }
    }

    // partial zt: rows {r,r+32,r+64,r+96}, cols [c0,c0+32)
    float a0 = 0.f, a1 = 0.f, a2 = 0.f, a3 = 0.f;
#pragma unroll
    for (int j = 0; j < 8; ++j) {
      float4 w4 = wq4[j];
      a0 += Greg[0][4 * j + 0] * w4.x + Greg[0][4 * j + 1] * w4.y +
            Greg[0][4 * j + 2] * w4.z + Greg[0][4 * j + 3] * w4.w;
      a1 += Greg[1][4 * j + 0] * w4.x + Greg[1][4 * j + 1] * w4.y +
            Greg[1][4 * j + 2] * w4.z + Greg[1][4 * j + 3] * w4.w;
      a2 += Greg[2][4 * j + 0] * w4.x + Greg[2][4 * j + 1] * w4.y +
            Greg[2][4 * j + 2] * w4.z + Greg[2][4 * j + 3] * w4.w;
      a3 += Greg[3][4 * j + 0] * w4.x + Greg[3][4 * j + 1] * w4.y +
            Greg[3][4 * j + 2] * w4.z + Greg[3][4 * j + 3] * w4.w;
    }
    part[ck][r] = a0;
    part[ck][r + 32] = a1;
    part[ck][r + 64] = a2;
    part[ck][r + 96] = a3;
    __syncthreads();  // B1: partials visible; wloc reads of iter `it` done

    if (t < 128) {
      float zold = zreg, yold = yreg;
      float w_old = RHO_C * zreg - yreg;
      Sreg = w_old - 0.6f * Sreg;       // S <- w + (1-alpha)*S
      float p = 0.0f;
#pragma unroll
      for (int c = 0; c < 16; ++c) p += part[c][t];
      float zt = p - dreg;
      float zh = ALPHA_C * zt + (1.0f - ALPHA_C) * zreg;
      float zc = zh + yreg * (1.0f / RHO_C);
      zc = fminf(fmaxf(zc, lreg), ureg);
      yreg += RHO_C * (zh - zc);
      zreg = zc;
      bool rowst = (__float_as_uint(zreg) == __float_as_uint(zold)) &&
                   (__float_as_uint(yreg) == __float_as_uint(yold));
      unsigned long long bal = __ballot(rowst);
      if ((t & 63) == 0) ownW[(it + 1) & 1][t >> 6] = (bal == ~0ull);
      if (t == 0) remOK[it & 1] = 1;    // reset the slot iter it+1 will AND into
      float wn = RHO_C * zreg - yreg;   // w_{it+1}[own row]
      wloc[s * 128 + t] = wn;
      if (it < NITERS - 1) {
        unsigned long long pk =
            ((unsigned long long)(rowst ? 1u : 0u) << 63) |
            ((unsigned long long)(unsigned)(it + 1) << 32) |
            (unsigned long long)__float_as_uint(wn);
        unsigned long long* wp = ((it + 1) & 1) ? wt1 : wt0;
        __hip_atomic_store(&wp[s * 128 + t], pk, __ATOMIC_RELAXED,
                           __HIP_MEMORY_SCOPE_AGENT);
      }
    } else if (it < NITERS - 1) {
      unsigned long long* wp = ((it + 1) & 1) ? wt1 : wt0;
      unsigned want = (unsigned)(it + 1);
      unsigned long long v;
      for (;;) {
        v = __hip_atomic_load(&wp[gr], __ATOMIC_RELAXED,
                              __HIP_MEMORY_SCOPE_AGENT);
        if ((unsigned)((v >> 32) & 0x7fffffffu) == want) break;
        __builtin_amdgcn_s_sleep(1);
      }
      wloc[gr] = __uint_as_float((unsigned)(v & 0xffffffffu));
      if (!(v >> 63)) remOK[(it + 1) & 1] = 0;  // remote row not stable
    }
  }

  if (t < 128) Sbuf[(size_t)b * 512 + s * 128 + t] = Sreg;
}

// ---------------------------------------------------------------------------
// K7: epilogue  x = Minv * (alpha * A^T S - q)
// ---------------------------------------------------------------------------
__global__ __launch_bounds__(256) void k_final(
    const float* __restrict__ A, const float* __restrict__ q,
    const float* __restrict__ Mi, const float* __restrict__ Sbuf,
    float* __restrict__ xout) {
  int b = blockIdx.x, t = threadIdx.x;
  __shared__ float Ssh[512];
  __shared__ float uu[256];
  for (int i = t; i < 512; i += 256) Ssh[i] = Sbuf[(size_t)b * 512 + i];
  __syncthreads();
  const float* Ab = A + (size_t)b * 131072;
  float acc = 0.0f;
  for (int m = 0; m < 512; ++m) acc += Ab[(size_t)m * 256 + t] * Ssh[m];
  uu[t] = ALPHA_C * acc - q[(size_t)b * 256 + t];
  __syncthreads();
  const float* Mb = Mi + (size_t)b * 65536;
  float x = 0.0f;
  for (int kk = 0; kk < 256; ++kk) x += Mb[(size_t)kk * 256 + t] * uu[kk];
  xout[(size_t)b * 256 + t] = x;
}

// ---------------------------------------------------------------------------
extern "C" void kernel_launch(void* const* d_in, const int* in_sizes, int n_in,
                              void* d_out, int out_size, void* d_ws, size_t ws_size,
                              hipStream_t stream) {
  (void)in_sizes; (void)n_in; (void)out_size; (void)ws_size;
  const float* P = (const float*)d_in[0];
  const float* q = (const float*)d_in[1];
  const float* Av = (const float*)d_in[2];
  const float* lv = (const float*)d_in[3];
  const float* uv = (const float*)d_in[4];
  float* xout = (float*)d_out;

  float* ws = (float*)d_ws;
  float* At = ws;                       // 64*256*512; dies after F GEMM
  float* F  = ws;                       // alias of At; dies after G GEMM
  float* Mi = ws + 8388608;             // 64*256*256
  float* Mk = ws + 12582912;            // dies after k_invert
  float* G  = ws + 12582912;            // 64*512*512 (over dead Mk)
  float* dv = ws + 29376512;            // 64*512
  float* Sbuf = ws + 29409280;          // 64*512
  unsigned long long* wtag = (unsigned long long*)ws;  // overlays dead At/F

  k_transpose<<<dim3(8, 16, 64), dim3(32, 8), 0, stream>>>(Av, At);
  // Mk = rho*At*At^T + diag(P+sigma): upper tiles only (symN=2 -> 3 tiles)
  k_ntgemm<<<dim3(3, 64), 256, 0, stream>>>(At, At, Mk, 256, 512,
                                            131072LL, 131072LL, 65536LL,
                                            RHO_C, P, 0, 2);
  k_mirror<<<dim3(28, 64), 256, 0, stream>>>(Mk, 256, 65536LL);
  k_invert<<<64, 512, 0, stream>>>(Mk, Mi);
  k_matvec_hd<<<64, 512, 0, stream>>>(Mi, q, At, dv);
  // F = A * Minv (full: 4x2 tiles)
  k_ntgemm<<<dim3(8, 64), 256, 0, stream>>>(Av, Mi, F, 256, 256,
                                            131072LL, 65536LL, 131072LL,
                                            1.0f, nullptr, 2, 0);
  // G = F * A^T: upper tiles only (symN=4 -> 10 tiles)
  k_ntgemm<<<dim3(10, 64), 256, 0, stream>>>(F, Av, G, 512, 256,
                                             131072LL, 131072LL, 262144LL,
                                             1.0f, nullptr, 0, 4);
  k_mirror<<<dim3(120, 64), 256, 0, stream>>>(G, 512, 262144LL);
  k_admm4<<<256, 512, 0, stream>>>(G, dv, lv, uv, wtag, Sbuf);
  k_final<<<64, 256, 0, stream>>>(Av, q, Mi, Sbuf, xout);
}

// Round 12
// 1712.335 us; speedup vs baseline: 1.0379x; 1.0379x over previous
//
#include <hip/hip_runtime.h>
#include <hip/hip_fp16.h>

#define N_VAR 256
#define M_CON 512
#define BATCH 64
#define SIGMA_C 1e-6f
#define RHO_C 0.1f
#define ALPHA_C 1.6f
#define NITERS 500

// ---------------------------------------------------------------------------
// K1: Mk = rho*A^T A + diag(P+sigma), TN GEMM straight from row-major A
// (no transpose kernel). 3 upper tiles: r=0->(0,0), 1->(0,1), 2->(1,1).
// Diagonal tiles are symmetric by construction (identical products, identical
// order) -> full direct write. Off-diag tile also writes its transpose via a
// 16x132 LDS chunk buffer (coalesced-ish). Double-buffered LDS staging.
// ---------------------------------------------------------------------------
__global__ __launch_bounds__(256) void k_mkgemm(const float* __restrict__ A,
                                                float* __restrict__ Mk,
                                                const float* __restrict__ P) {
  int b = blockIdx.y;
  int r3 = blockIdx.x;                 // 0,1,2
  int ti = (r3 == 2) ? 1 : 0, tj = (r3 == 0) ? 0 : 1;
  int i0 = ti * 128, j0 = tj * 128;
  bool diag = (ti == tj);
  const float* Ab = A + (size_t)b * 131072;
  float* Cb = Mk + (size_t)b * 65536;

  __shared__ float Xs[2][16][132];
  __shared__ float Ys[2][16][132];
  __shared__ float TB[16][132];

  int tid = threadIdx.x;
  int tx = tid & 15, ty = tid >> 4;

  float acc[8][8];
#pragma unroll
  for (int r = 0; r < 8; ++r)
#pragma unroll
    for (int c = 0; c < 8; ++c) acc[r][c] = 0.0f;

  float4 px[2], py[2];
  auto prefetch = [&](int kk) {
#pragma unroll
    for (int v = 0; v < 2; ++v) {
      int idx = v * 256 + tid;
      int mm = idx >> 5, f4 = idx & 31;
      px[v] = *(const float4*)(Ab + (size_t)(kk + mm) * 256 + i0 + 4 * f4);
      if (!diag)
        py[v] = *(const float4*)(Ab + (size_t)(kk + mm) * 256 + j0 + 4 * f4);
    }
  };
  auto commit = [&](int buf) {
#pragma unroll
    for (int v = 0; v < 2; ++v) {
      int idx = v * 256 + tid;
      int mm = idx >> 5, f4 = idx & 31;
      *(float4*)&Xs[buf][mm][4 * f4] = px[v];
      if (!diag) *(float4*)&Ys[buf][mm][4 * f4] = py[v];
    }
  };

  prefetch(0);
  commit(0);
  __syncthreads();

  for (int kt = 0; kt < 32; ++kt) {  // K = 512
    int cur = kt & 1;
    if (kt + 1 < 32) prefetch((kt + 1) * 16);
#pragma unroll
    for (int k = 0; k < 16; ++k) {
      float xr[8], yr[8];
      *(float4*)&xr[0] = *(float4*)&Xs[cur][k][ty * 8];
      *(float4*)&xr[4] = *(float4*)&Xs[cur][k][ty * 8 + 4];
      const float* yb = diag ? &Xs[cur][k][0] : &Ys[cur][k][0];
      *(float4*)&yr[0] = *(const float4*)&yb[tx * 8];
      *(float4*)&yr[4] = *(const float4*)&yb[tx * 8 + 4];
#pragma unroll
      for (int r = 0; r < 8; ++r)
#pragma unroll
        for (int c = 0; c < 8; ++c) acc[r][c] += xr[r] * yr[c];
    }
    if (kt + 1 < 32) commit(cur ^ 1);
    __syncthreads();
  }

  // normal write (+ diag add)
#pragma unroll
  for (int r = 0; r < 8; ++r) {
    int gi = i0 + ty * 8 + r;
#pragma unroll
    for (int c = 0; c < 8; ++c) {
      int gj = j0 + tx * 8 + c;
      float val = acc[r][c] * RHO_C;
      if (gi == gj) val += P[(size_t)b * 256 + gi] + SIGMA_C;
      Cb[(size_t)gi * 256 + gj] = val;
      acc[r][c] = val;  // keep scaled value for mirror
    }
  }
  if (!diag) {  // transposed write via LDS chunks (no diag elements here)
    for (int ci = 0; ci < 8; ++ci) {
      __syncthreads();
      if ((ty >> 1) == ci) {
        int base = (ty & 1) * 8;
#pragma unroll
        for (int r = 0; r < 8; ++r)
#pragma unroll
          for (int c = 0; c < 8; ++c) TB[base + r][tx * 8 + c] = acc[r][c];
      }
      __syncthreads();
      int jj = tid >> 1, half = tid & 1;
      float o[8];
#pragma unroll
      for (int e = 0; e < 8; ++e) o[e] = TB[8 * half + e][jj];
      float* dst = Cb + (size_t)(j0 + jj) * 256 + i0 + ci * 16 + 8 * half;
      *(float4*)dst = make_float4(o[0], o[1], o[2], o[3]);
      *(float4*)(dst + 4) = make_float4(o[4], o[5], o[6], o[7]);
    }
  }
}

// ---------------------------------------------------------------------------
// K2: batched NT GEMM, double-buffered LDS, padded rows (132). symN>0: upper
// tiles only; diag tiles written full; off-diag tiles ALSO write transpose
// via LDS chunks (replaces the k_mirror kernel).
// ---------------------------------------------------------------------------
__global__ __launch_bounds__(256) void k_ntgemm(
    const float* __restrict__ X, const float* __restrict__ Y,
    float* __restrict__ C, int J, int K,
    long long bsX, long long bsY, long long bsC, float alpha,
    int tilesJ, int symN) {
  int b = blockIdx.y;
  int ti, tj;
  if (symN > 0) {
    int r = blockIdx.x;
    ti = 0;
    while (r >= symN - ti) { r -= (symN - ti); ++ti; }
    tj = ti + r;
  } else {
    ti = blockIdx.x / tilesJ;
    tj = blockIdx.x % tilesJ;
  }
  int i0 = ti * 128, j0 = tj * 128;
  const float* Xb = X + (size_t)b * bsX;
  const float* Yb = Y + (size_t)b * bsY;
  float* Cb = C + (size_t)b * bsC;
  __shared__ float Xs[2][16][132];
  __shared__ float Ys[2][16][132];
  __shared__ float TB[16][132];
  int tid = threadIdx.x;
  int tx = tid & 15, ty = tid >> 4;
  int row0 = tid >> 2, k40 = (tid & 3) * 4;

  float acc[8][8];
#pragma unroll
  for (int r = 0; r < 8; ++r)
#pragma unroll
    for (int c = 0; c < 8; ++c) acc[r][c] = 0.0f;

  float4 rx0, rx1, ry0, ry1;
  auto prefetch = [&](int kk) {
    rx0 = *(const float4*)(Xb + (size_t)(i0 + row0) * K + kk + k40);
    rx1 = *(const float4*)(Xb + (size_t)(i0 + row0 + 64) * K + kk + k40);
    ry0 = *(const float4*)(Yb + (size_t)(j0 + row0) * K + kk + k40);
    ry1 = *(const float4*)(Yb + (size_t)(j0 + row0 + 64) * K + kk + k40);
  };
  auto commit = [&](int buf) {
    Xs[buf][k40 + 0][row0] = rx0.x; Xs[buf][k40 + 1][row0] = rx0.y;
    Xs[buf][k40 + 2][row0] = rx0.z; Xs[buf][k40 + 3][row0] = rx0.w;
    Xs[buf][k40 + 0][row0 + 64] = rx1.x; Xs[buf][k40 + 1][row0 + 64] = rx1.y;
    Xs[buf][k40 + 2][row0 + 64] = rx1.z; Xs[buf][k40 + 3][row0 + 64] = rx1.w;
    Ys[buf][k40 + 0][row0] = ry0.x; Ys[buf][k40 + 1][row0] = ry0.y;
    Ys[buf][k40 + 2][row0] = ry0.z; Ys[buf][k40 + 3][row0] = ry0.w;
    Ys[buf][k40 + 0][row0 + 64] = ry1.x; Ys[buf][k40 + 1][row0 + 64] = ry1.y;
    Ys[buf][k40 + 2][row0 + 64] = ry1.z; Ys[buf][k40 + 3][row0 + 64] = ry1.w;
  };

  int nkt = K >> 4;
  prefetch(0);
  commit(0);
  __syncthreads();

  for (int kt = 0; kt < nkt; ++kt) {
    int cur = kt & 1;
    if (kt + 1 < nkt) prefetch((kt + 1) * 16);
#pragma unroll
    for (int k = 0; k < 16; ++k) {
      float xr[8], yr[8];
      *(float4*)&xr[0] = *(float4*)&Xs[cur][k][ty * 8];
      *(float4*)&xr[4] = *(float4*)&Xs[cur][k][ty * 8 + 4];
      *(float4*)&yr[0] = *(float4*)&Ys[cur][k][tx * 8];
      *(float4*)&yr[4] = *(float4*)&Ys[cur][k][tx * 8 + 4];
#pragma unroll
      for (int r = 0; r < 8; ++r)
#pragma unroll
        for (int c = 0; c < 8; ++c) acc[r][c] += xr[r] * yr[c];
    }
    if (kt + 1 < nkt) commit(cur ^ 1);
    __syncthreads();
  }

#pragma unroll
  for (int r = 0; r < 8; ++r) {
    int gi = i0 + ty * 8 + r;
#pragma unroll
    for (int c = 0; c < 8; ++c) {
      int gj = j0 + tx * 8 + c;
      float val = acc[r][c] * alpha;
      Cb[(size_t)gi * J + gj] = val;
      acc[r][c] = val;
    }
  }
  if (symN > 0 && ti != tj) {  // fused transposed write
    for (int ci = 0; ci < 8; ++ci) {
      __syncthreads();
      if ((ty >> 1) == ci) {
        int base = (ty & 1) * 8;
#pragma unroll
        for (int r = 0; r < 8; ++r)
#pragma unroll
          for (int c = 0; c < 8; ++c) TB[base + r][tx * 8 + c] = acc[r][c];
      }
      __syncthreads();
      int jj = tid >> 1, half = tid & 1;
      float o[8];
#pragma unroll
      for (int e = 0; e < 8; ++e) o[e] = TB[8 * half + e][jj];
      float* dst = Cb + (size_t)(j0 + jj) * J + i0 + ci * 16 + 8 * half;
      *(float4*)dst = make_float4(o[0], o[1], o[2], o[3]);
      *(float4*)(dst + 4) = make_float4(o[4], o[5], o[6], o[7]);
    }
  }
}

// ---------------------------------------------------------------------------
// K3: BLOCKED Gauss-Jordan inversion, NB=8 (round-7 version).
// ---------------------------------------------------------------------------
__global__ __launch_bounds__(512, 2) void k_invert(const float* __restrict__ Mk,
                                                   float* __restrict__ Mi) {
  int b = blockIdx.x;
  const float* src = Mk + (size_t)b * 65536;
  float* dst = Mi + (size_t)b * 65536;
  int t = threadIdx.x;
  int c = t & 255, rh = t >> 8;

  float a[128];
#pragma unroll
  for (int j = 0; j < 128; ++j) a[j] = src[(size_t)(rh * 128 + j) * 256 + c];

  __shared__ float colPan[256][8];
  __shared__ float rowPan[2][8][260];
  __shared__ float PiSh[64];
  __shared__ float Rp[8][260];

  int rh_s = __builtin_amdgcn_readfirstlane(rh);
  int cw_s = __builtin_amdgcn_readfirstlane((t >> 6) & 3);

  if (rh == 0) {
#pragma unroll
    for (int j = 0; j < 8; ++j) rowPan[0][j][c] = a[j];
  }
  __syncthreads();

  for (int s = 0; s < 32; ++s) {
    int kb = s * 8;
    int cur = s & 1, nxt = cur ^ 1;
    int kh = kb >> 7, kj = kb & 127;
    int khn = (kb + 8) >> 7, kjn = (kb + 8) & 127;
    bool mycol = (c >= kb) && (c < kb + 8);

    if (cw_s == (kb >> 6)) {
      if (mycol) {
        int f = c - kb;
#pragma unroll
        for (int j = 0; j < 128; ++j) colPan[rh * 128 + j][f] = a[j];
      }
    }
    if (t < 64) {
      int e = t >> 3, f = t & 7;
      float p = rowPan[cur][e][kb + f];
#pragma unroll
      for (int k2 = 0; k2 < 8; ++k2) {
        float piv = __shfl(p, k2 * 8 + k2);
        float rv = __shfl(p, k2 * 8 + f);
        float cv = __shfl(p, e * 8 + k2);
        float pivinv = 1.0f / piv;
        float srv = rv * pivinv;
        float gen = p - cv * srv;
        p = gen;
        if (e == k2) p = srv;
        if (f == k2) p = -cv * pivinv;
        if (e == k2 && f == k2) p = pivinv;
      }
      PiSh[t] = p;
    }
    __syncthreads();

    float rpan[8];
#pragma unroll
    for (int f2 = 0; f2 < 8; ++f2) rpan[f2] = rowPan[cur][f2][c];
    float rp[8];
#pragma unroll
    for (int e = 0; e < 8; ++e) {
      float4 p0 = *(const float4*)&PiSh[e * 8];
      float4 p1 = *(const float4*)&PiSh[e * 8 + 4];
      rp[e] = p0.x * rpan[0] + p0.y * rpan[1] + p0.z * rpan[2] + p0.w * rpan[3] +
              p1.x * rpan[4] + p1.y * rpan[5] + p1.z * rpan[6] + p1.w * rpan[7];
    }
    if (cw_s == (kb >> 6)) {
      if (mycol) {
        int f = c - kb;
#pragma unroll
        for (int e = 0; e < 8; ++e) rp[e] = PiSh[e * 8 + f];
      }
    }
#pragma unroll
    for (int e = 0; e < 8; ++e) Rp[e][c] = rp[e];

    bool myhalfk = (rh_s == kh);
    bool stashw = (s != 31) && (rh_s == khn);
#pragma unroll
    for (int j = 0; j < 128; ++j) {
      float4 c0 = *(const float4*)&colPan[rh * 128 + j][0];
      float4 c1 = *(const float4*)&colPan[rh * 128 + j][4];
      float aold = a[j];
      float nv = aold -
                 (c0.x * rp[0] + c0.y * rp[1] + c0.z * rp[2] + c0.w * rp[3] +
                  c1.x * rp[4] + c1.y * rp[5] + c1.z * rp[6] + c1.w * rp[7]);
      if (mycol) nv -= aold;
      if (myhalfk && j >= kj && j < kj + 8)
        nv = Rp[j - kj][c];
      a[j] = nv;
      if (stashw && j >= kjn && j < kjn + 8)
        rowPan[nxt][j - kjn][c] = nv;
    }
    __syncthreads();
  }

#pragma unroll
  for (int j = 0; j < 128; ++j) dst[(size_t)(rh * 128 + j) * 256 + c] = a[j];
}

// ---------------------------------------------------------------------------
// K4: fused  h = Minv*q ; d = A*h  (A row-major; per-wave row dots + shuffle
// reduce -> no transposed A needed anywhere).
// ---------------------------------------------------------------------------
__global__ __launch_bounds__(512) void k_matvec_hd(
    const float* __restrict__ Mi, const float* __restrict__ q,
    const float* __restrict__ A, float* __restrict__ d) {
  int b = blockIdx.x, t = threadIdx.x;
  __shared__ float qs[256];
  __shared__ __align__(16) float hs[256];
  if (t < 256) qs[t] = q[(size_t)b * 256 + t];
  __syncthreads();
  if (t < 256) {
    const float* Mb = Mi + (size_t)b * 65536;
    float acc = 0.0f;
    for (int k = 0; k < 256; ++k) acc += Mb[(size_t)k * 256 + t] * qs[k];
    hs[t] = acc;
  }
  __syncthreads();
  int wv = t >> 6, l = t & 63;
  const float* Ab = A + (size_t)b * 131072;
  float4 h4 = *(const float4*)&hs[4 * l];
  for (int i = 0; i < 64; ++i) {
    int m = wv * 64 + i;
    float4 a4 = *(const float4*)(Ab + (size_t)m * 256 + 4 * l);
    float p = a4.x * h4.x + a4.y * h4.y + a4.z * h4.z + a4.w * h4.w;
#pragma unroll
    for (int off = 32; off >= 1; off >>= 1) p += __shfl_down(p, off);
    if (l == 0) d[(size_t)b * 512 + m] = p;
  }
}

// ---------------------------------------------------------------------------
// K6: ADMM loop — round-10 version (proven 763 us; early-exit reverted:
// round-11 showed no bitwise fixed point occurs, flags cost 57 us).
// 4 CUs/batch, register-resident G, packed (tag|value) u64 relaxed
// agent-atomic exchange, parity double-buffered. 2 barriers/iter.
// ---------------------------------------------------------------------------
__global__ __launch_bounds__(512, 2) void k_admm4(
    const float* __restrict__ G, const float* __restrict__ dvec,
    const float* __restrict__ lv, const float* __restrict__ uv,
    unsigned long long* __restrict__ wtag, float* __restrict__ Sbuf) {
  int g = blockIdx.x;
  int b = (g & 7) + 8 * ((g >> 3) & 7);
  int s = g >> 6;
  int t = threadIdx.x;
  int r = t & 31, ck = t >> 5;
  int c0 = ck * 32;

  __shared__ __align__(16) float wloc[512];
  __shared__ float part[16][132];

  const float* Gb = G + (size_t)b * 262144;
  float Greg[4][32];
#pragma unroll
  for (int k = 0; k < 4; ++k) {
    const float* gp = Gb + (size_t)(s * 128 + r + 32 * k) * 512 + c0;
#pragma unroll
    for (int j = 0; j < 8; ++j) {
      float4 v = *(const float4*)(gp + 4 * j);
      Greg[k][4 * j + 0] = v.x; Greg[k][4 * j + 1] = v.y;
      Greg[k][4 * j + 2] = v.z; Greg[k][4 * j + 3] = v.w;
    }
  }

  float zreg = 0.0f, yreg = 0.0f, Sreg = 0.0f;
  float lreg = 0.0f, ureg = 0.0f, dreg = 0.0f;
  if (t < 128) {
    lreg = lv[(size_t)b * 512 + s * 128 + t];
    ureg = uv[(size_t)b * 512 + s * 128 + t];
    dreg = dvec[(size_t)b * 512 + s * 128 + t];
  }
  wloc[t] = 0.0f;  // w_0 = 0

  unsigned long long* wt0 = wtag + (size_t)b * 512;
  unsigned long long* wt1 = wtag + 32768 + (size_t)b * 512;
  int gr = (s * 128 + t) & 511;
  const float4* wq4 = (const float4*)(wloc + c0);

  for (int it = 0; it < NITERS; ++it) {
    __syncthreads();  // Btop: wloc == w_it everywhere

    float a0 = 0.f, a1 = 0.f, a2 = 0.f, a3 = 0.f;
#pragma unroll
    for (int j = 0; j < 8; ++j) {
      float4 w4 = wq4[j];
      a0 += Greg[0][4 * j + 0] * w4.x + Greg[0][4 * j + 1] * w4.y +
            Greg[0][4 * j + 2] * w4.z + Greg[0][4 * j + 3] * w4.w;
      a1 += Greg[1][4 * j + 0] * w4.x + Greg[1][4 * j + 1] * w4.y +
            Greg[1][4 * j + 2] * w4.z + Greg[1][4 * j + 3] * w4.w;
      a2 += Greg[2][4 * j + 0] * w4.x + Greg[2][4 * j + 1] * w4.y +
            Greg[2][4 * j + 2] * w4.z + Greg[2][4 * j + 3] * w4.w;
      a3 += Greg[3][4 * j + 0] * w4.x + Greg[3][4 * j + 1] * w4.y +
            Greg[3][4 * j + 2] * w4.z + Greg[3][4 * j + 3] * w4.w;
    }
    part[ck][r] = a0;
    part[ck][r + 32] = a1;
    part[ck][r + 64] = a2;
    part[ck][r + 96] = a3;
    __syncthreads();  // B1: partials visible; wloc reads of iter `it` done

    if (t < 128) {
      float w_old = RHO_C * zreg - yreg;
      Sreg = w_old - 0.6f * Sreg;       // S <- w + (1-alpha)*S
      float p = 0.0f;
#pragma unroll
      for (int c = 0; c < 16; ++c) p += part[c][t];
      float zt = p - dreg;
      float zh = ALPHA_C * zt + (1.0f - ALPHA_C) * zreg;
      float zc = zh + yreg * (1.0f / RHO_C);
      zc = fminf(fmaxf(zc, lreg), ureg);
      yreg += RHO_C * (zh - zc);
      zreg = zc;
      float wn = RHO_C * zreg - yreg;   // w_{it+1}[own row]
      wloc[s * 128 + t] = wn;
      if (it < NITERS - 1) {
        unsigned long long pk =
            ((unsigned long long)(unsigned)(it + 1) << 32) |
            (unsigned long long)__float_as_uint(wn);
        unsigned long long* wp = ((it + 1) & 1) ? wt1 : wt0;
        __hip_atomic_store(&wp[s * 128 + t], pk, __ATOMIC_RELAXED,
                           __HIP_MEMORY_SCOPE_AGENT);
      }
    } else if (it < NITERS - 1) {
      unsigned long long* wp = ((it + 1) & 1) ? wt1 : wt0;
      unsigned want = (unsigned)(it + 1);
      unsigned long long v;
      for (;;) {
        v = __hip_atomic_load(&wp[gr], __ATOMIC_RELAXED,
                              __HIP_MEMORY_SCOPE_AGENT);
        if ((unsigned)(v >> 32) == want) break;
        __builtin_amdgcn_s_sleep(1);
      }
      wloc[gr] = __uint_as_float((unsigned)(v & 0xffffffffu));
    }
  }

  if (t < 128) Sbuf[(size_t)b * 512 + s * 128 + t] = Sreg;
}

// ---------------------------------------------------------------------------
// K7: epilogue  x = Minv * (alpha * A^T S - q)
// ---------------------------------------------------------------------------
__global__ __launch_bounds__(256) void k_final(
    const float* __restrict__ A, const float* __restrict__ q,
    const float* __restrict__ Mi, const float* __restrict__ Sbuf,
    float* __restrict__ xout) {
  int b = blockIdx.x, t = threadIdx.x;
  __shared__ float Ssh[512];
  __shared__ float uu[256];
  for (int i = t; i < 512; i += 256) Ssh[i] = Sbuf[(size_t)b * 512 + i];
  __syncthreads();
  const float* Ab = A + (size_t)b * 131072;
  float acc = 0.0f;
  for (int m = 0; m < 512; ++m) acc += Ab[(size_t)m * 256 + t] * Ssh[m];
  uu[t] = ALPHA_C * acc - q[(size_t)b * 256 + t];
  __syncthreads();
  const float* Mb = Mi + (size_t)b * 65536;
  float x = 0.0f;
  for (int kk = 0; kk < 256; ++kk) x += Mb[(size_t)kk * 256 + t] * uu[kk];
  xout[(size_t)b * 256 + t] = x;
}

// ---------------------------------------------------------------------------
extern "C" void kernel_launch(void* const* d_in, const int* in_sizes, int n_in,
                              void* d_out, int out_size, void* d_ws, size_t ws_size,
                              hipStream_t stream) {
  (void)in_sizes; (void)n_in; (void)out_size; (void)ws_size;
  const float* P = (const float*)d_in[0];
  const float* q = (const float*)d_in[1];
  const float* Av = (const float*)d_in[2];
  const float* lv = (const float*)d_in[3];
  const float* uv = (const float*)d_in[4];
  float* xout = (float*)d_out;

  float* ws = (float*)d_ws;
  float* F  = ws;                       // 64*256*512; dies after G GEMM
  float* Mi = ws + 8388608;             // 64*256*256
  float* Mk = ws + 12582912;            // dies after k_invert
  float* G  = ws + 12582912;            // 64*512*512 (over dead Mk)
  float* dv = ws + 29376512;            // 64*512
  float* Sbuf = ws + 29409280;          // 64*512
  unsigned long long* wtag = (unsigned long long*)ws;  // overlays dead F

  // Mk = rho*A^T A + diag(P+sigma)  (TN, 3 upper tiles, self-mirroring)
  k_mkgemm<<<dim3(3, 64), 256, 0, stream>>>(Av, Mk, P);
  k_invert<<<64, 512, 0, stream>>>(Mk, Mi);
  k_matvec_hd<<<64, 512, 0, stream>>>(Mi, q, Av, dv);
  // F = A * Minv (full: 4x2 tiles)
  k_ntgemm<<<dim3(8, 64), 256, 0, stream>>>(Av, Mi, F, 256, 256,
                                            131072LL, 65536LL, 131072LL,
                                            1.0f, 2, 0);
  // G = F * A^T: upper tiles, fused transposed write
  k_ntgemm<<<dim3(10, 64), 256, 0, stream>>>(F, Av, G, 512, 256,
                                             131072LL, 131072LL, 262144LL,
                                             1.0f, 0, 4);
  k_admm4<<<256, 512, 0, stream>>>(G, dv, lv, uv, wtag, Sbuf);
  k_final<<<64, 256, 0, stream>>>(Av, q, Mi, Sbuf, xout);
}